// Round 6
// baseline (387.438 us; speedup 1.0000x reference)
//
#include <hip/hip_runtime.h>

#define TS 3584
#define VS 1792
#define TPF 448
#define NHEAD 12
#define HDIM 128
#define DMODEL 1536
// ATTN_SCALE * log2(e): folded into q during rmsnorm_rope so QK^T scores are
// already in log2 domain (softmax uses exp2).
#define QK_PRESCALE (0.08838834764831845f * 1.4426950408889634f)

typedef unsigned short u16;
typedef unsigned int u32;
typedef unsigned long long u64;
typedef __attribute__((ext_vector_type(8))) short bf16x8;
typedef __attribute__((ext_vector_type(4))) float f32x4;

__device__ __forceinline__ float u2f(u32 u) { union { u32 u; float f; } c; c.u = u; return c.f; }
__device__ __forceinline__ float blo(u32 u) { return u2f(u << 16); }
__device__ __forceinline__ float bhi(u32 u) { return u2f(u & 0xffff0000u); }
__device__ __forceinline__ u16 f2b(float f) {
  union { float f; u32 u; } c; c.f = f;
  return (u16)((c.u + 0x7fffu + ((c.u >> 16) & 1u)) >> 16);
}

__device__ __forceinline__ float exp2fast(float x) {
#if __has_builtin(__builtin_amdgcn_exp2f)
  return __builtin_amdgcn_exp2f(x);
#else
  float r; asm("v_exp_f32 %0, %1" : "=v"(r) : "v"(x)); return r;
#endif
}

// async global -> LDS, 16B per lane; LDS dest is wave-uniform base
// (HW writes base + lane*16), global src is per-lane (pre-swizzled).
__device__ __forceinline__ void gl16(const u16* g, u16* l) {
  __builtin_amdgcn_global_load_lds(
      (const __attribute__((address_space(1))) void*)g,
      (__attribute__((address_space(3))) void*)l, 16, 0, 0);
}

// Pack fp32 tensors to bf16 (RNE). z: 0=x, 1..3=q/k/v weights (concat), 4=o_w.
__global__ __launch_bounds__(256) void convert_bf16(
    const float* __restrict__ x, const float* __restrict__ qw,
    const float* __restrict__ kw, const float* __restrict__ vw,
    const float* __restrict__ ow, u16* __restrict__ xb,
    u16* __restrict__ wqkv, u16* __restrict__ owb) {
  const int z = blockIdx.y;
  const float* src;
  u16* dst;
  int n8;
  if (z == 0)      { src = x;  dst = xb;  n8 = TS * DMODEL / 8; }
  else if (z == 4) { src = ow; dst = owb; n8 = DMODEL * DMODEL / 8; }
  else {
    src = (z == 1) ? qw : (z == 2) ? kw : vw;
    dst = wqkv + (size_t)(z - 1) * DMODEL * DMODEL;
    n8 = DMODEL * DMODEL / 8;
  }
  const int idx = blockIdx.x * 256 + threadIdx.x;
  if (idx >= n8) return;
  const float4 a = ((const float4*)src)[2 * idx];
  const float4 b = ((const float4*)src)[2 * idx + 1];
  uint4 o;
  o.x = (u32)f2b(a.x) | ((u32)f2b(a.y) << 16);
  o.y = (u32)f2b(a.z) | ((u32)f2b(a.w) << 16);
  o.z = (u32)f2b(b.x) | ((u32)f2b(b.y) << 16);
  o.w = (u32)f2b(b.z) | ((u32)f2b(b.w) << 16);
  ((uint4*)dst)[idx] = o;
}

// MFMA NT GEMM: C[m,n] = sum_k A[m,k]*W[n,k] + bias[n]. A,W bf16 K-major, K=1536.
// 128x128 tile, BK=64, 256 thr = 4 waves, each wave 64x64 via 4x4 mfma 16x16x32.
// Staging via global_load_lds (pre-swizzled global src) + bijective XCD swizzle.
// QKV v-section blocks (exactly one head wide) write vt TRANSPOSED directly
// via a swizzled LDS bounce -> no separate transpose kernel.
template <bool QKV>
__global__ __launch_bounds__(256) void gemm_mfma(
    const u16* __restrict__ A, const u16* __restrict__ W,
    const float* __restrict__ b0, const float* __restrict__ b1,
    const float* __restrict__ b2,
    u16* __restrict__ o0, u16* __restrict__ o1, u16* __restrict__ o2,
    float* __restrict__ of) {
  __shared__ __align__(16) u16 SH[128 * 128];   // Als | Bls; reused by v-epilogue
  u16* const Als = SH;
  u16* const Bls = SH + 128 * 64;
  const int t = threadIdx.x;
  const int wave = t >> 6, lane = t & 63, col = lane & 15, quad = lane >> 4;
  // XCD swizzle (grids are multiples of 8 -> simple form is bijective).
  const int nwg = gridDim.x * gridDim.y;
  const int dlin = blockIdx.y * gridDim.x + blockIdx.x;
  const int wk = (dlin & 7) * (nwg >> 3) + (dlin >> 3);
  const int by = wk / gridDim.x, bx = wk - by * gridDim.x;
  const int m0 = by * 128, n0 = bx * 128;
  const int wm = (wave & 1) * 64, wn = (wave >> 1) * 64;

  // per-lane pre-swizzled staging sources: LDS linear dest idx*8 holds
  // global chunk (idx&7)^((idx>>3)&7) of row idx>>3 (matches read swizzle).
  const int srow = lane >> 3;                  // 0..7
  const int sch = (lane & 7) ^ srow;           // source chunk
  const u16* pA[4];
  const u16* pB[4];
#pragma unroll
  for (int i = 0; i < 4; ++i) {
    const int r = i * 32 + wave * 8 + srow;
    pA[i] = A + (size_t)(m0 + r) * DMODEL + sch * 8;
    pB[i] = W + (size_t)(n0 + r) * DMODEL + sch * 8;
  }

  f32x4 acc[4][4];
#pragma unroll
  for (int i = 0; i < 4; ++i)
#pragma unroll
    for (int j = 0; j < 4; ++j) acc[i][j] = (f32x4){0.f, 0.f, 0.f, 0.f};

  for (int k0 = 0; k0 < DMODEL; k0 += 64) {
    __syncthreads();
#pragma unroll
    for (int i = 0; i < 4; ++i) {
      gl16(pA[i] + k0, &Als[i * 2048 + wave * 512]);
      gl16(pB[i] + k0, &Bls[i * 2048 + wave * 512]);
    }
    __syncthreads();   // compiler drains vmcnt before s_barrier
#pragma unroll
    for (int s = 0; s < 2; ++s) {
      bf16x8 af[4], bv[4];
#pragma unroll
      for (int i = 0; i < 4; ++i) {
        const int r = wm + i * 16 + col;
        af[i] = *(const bf16x8*)&Als[r * 64 + (((s * 4 + quad) ^ (r & 7)) * 8)];
      }
#pragma unroll
      for (int j = 0; j < 4; ++j) {
        const int r = wn + j * 16 + col;
        bv[j] = *(const bf16x8*)&Bls[r * 64 + (((s * 4 + quad) ^ (r & 7)) * 8)];
      }
#pragma unroll
      for (int i = 0; i < 4; ++i)
#pragma unroll
        for (int j = 0; j < 4; ++j)
          acc[i][j] = __builtin_amdgcn_mfma_f32_16x16x32_bf16(af[i], bv[j], acc[i][j], 0, 0, 0);
    }
  }

  if constexpr (QKV) {
    const int sec = n0 / DMODEL;   // block-uniform (128-wide sections)
    if (sec == 2) {
      // ---- fused V transpose: acc -> LDS [hd][tok] (chunk-XOR swizzle) -> vt ----
      __syncthreads();             // all waves done reading Als/Bls
#pragma unroll
      for (int j = 0; j < 4; ++j) {
        const int hdl = wn + j * 16 + col;           // 0..127 (= head-local hd)
        const float bias = b2[n0 - 2 * DMODEL + hdl];
#pragma unroll
        for (int i = 0; i < 4; ++i) {
          const int tokl = wm + i * 16 + quad * 4;   // 0..124 (4 consecutive)
          u64 pk = (u64)f2b(acc[i][j][0] + bias) |
                   ((u64)f2b(acc[i][j][1] + bias) << 16) |
                   ((u64)f2b(acc[i][j][2] + bias) << 32) |
                   ((u64)f2b(acc[i][j][3] + bias) << 48);
          *(u64*)&SH[hdl * 128 + (((tokl >> 3) ^ (hdl & 15)) * 8) + (tokl & 7)] = pk;
        }
      }
      __syncthreads();
      const int hgl = (n0 - 2 * DMODEL) >> 7;        // global head
#pragma unroll
      for (int it = 0; it < 8; ++it) {
        const int idx = t + it * 256;
        const int row = idx >> 4, ch = idx & 15;
        uint4 w = *(const uint4*)&SH[row * 128 + ((ch ^ (row & 15)) * 8)];
        *(uint4*)(o2 + (size_t)(hgl * HDIM + row) * TS + m0 + ch * 8) = w;
      }
      return;
    }
    // ---- q / k sections: row-major bf16 + bias ----
    u16* dst = (sec == 0) ? o0 : o1;
    const float* bp = (sec == 0) ? b0 : b1;
#pragma unroll
    for (int j = 0; j < 4; ++j) {
      const int nn = n0 - sec * DMODEL + wn + j * 16 + col;
      const float bias = bp[nn];
#pragma unroll
      for (int i = 0; i < 4; ++i) {
        const int mb = m0 + wm + i * 16 + quad * 4;
#pragma unroll
        for (int r = 0; r < 4; ++r)
          dst[(size_t)(mb + r) * DMODEL + nn] = f2b(acc[i][j][r] + bias);
      }
    }
  } else {
#pragma unroll
    for (int j = 0; j < 4; ++j) {
      const int ng = n0 + wn + j * 16 + col;
      const float bias = b0[ng];
#pragma unroll
      for (int i = 0; i < 4; ++i) {
        const int mb = m0 + wm + i * 16 + quad * 4;
#pragma unroll
        for (int r = 0; r < 4; ++r)
          of[(size_t)(mb + r) * DMODEL + ng] = acc[i][j][r] + bias;
      }
    }
  }
}

// In-place RMSNorm(+weight) then RoPE on bf16 rows. blockIdx.x = token; y: 0=q,1=k.
__global__ __launch_bounds__(256) void rmsnorm_rope(
    u16* qbuf, u16* kbuf, const float* __restrict__ freqs,
    const float* __restrict__ nqw, const float* __restrict__ nkw) {
  const int tok = blockIdx.x;
  u32* row = (u32*)((blockIdx.y == 0 ? qbuf : kbuf) + (size_t)tok * DMODEL);
  const float* w = blockIdx.y == 0 ? nqw : nkw;
  const int t = threadIdx.x;
  const u32 u0 = row[t], u1 = row[t + 256], u2 = row[t + 512];
  float px[3] = { blo(u0), blo(u1), blo(u2) };
  float py[3] = { bhi(u0), bhi(u1), bhi(u2) };
  float ss = px[0] * px[0] + py[0] * py[0] + px[1] * px[1] + py[1] * py[1] +
             px[2] * px[2] + py[2] * py[2];
#pragma unroll
  for (int off = 32; off; off >>= 1) ss += __shfl_xor(ss, off);
  __shared__ float red[4];
  if ((t & 63) == 0) red[t >> 6] = ss;
  __syncthreads();
  float rstd = rsqrtf((red[0] + red[1] + red[2] + red[3]) * (1.0f / DMODEL) + 1e-6f);
  if (blockIdx.y == 0) rstd *= QK_PRESCALE;
  const int p = tok % VS;
  const int fi = p / TPF, rem = p % TPF, hi = rem / 28, wi = rem % 28;
#pragma unroll
  for (int jj = 0; jj < 3; ++jj) {
    const int pj = t + jj * 256;
    const int i = pj & 63;
    const int prow = (i < 22) ? fi : ((i < 43) ? hi : wi);
    const float ang = freqs[prow * 64 + i];
    float sn, cs;
    sincosf(ang, &sn, &cs);
    const float a = px[jj] * rstd * w[2 * pj], b = py[jj] * rstd * w[2 * pj + 1];
    row[pj] = (u32)f2b(a * cs - b * sn) | ((u32)f2b(a * sn + b * cs) << 16);
  }
}

// MFMA flash attention over union key set (in-view 1792 + cross-view same-frame 448).
// v7: split-KV pairs. 256 thr = 4 waves; pair P = waves {2P, 2P+1} processes
// key-tiles [P*35, P*35+35) with its OWN double-buffered K/V LDS (64 KB total).
// Each wave handles 32 q-rows (row-sets A/B) -> every K/V ds_read feeds 2 MFMAs
// (v6's reuse) while per-CU wave count is back to v4's level. Partner waves
// (w ^ 2) merge partial (m,l,acc) via an LDS LSE-combine epilogue.
__global__ __launch_bounds__(256) void attn_mfma(
    const u16* __restrict__ q, const u16* __restrict__ k,
    const u16* __restrict__ vt, u16* __restrict__ fused) {
  __shared__ __align__(16) u16 Kls[2 * 2 * 4096];   // [pair][buf][32x128]
  __shared__ __align__(16) u16 Vls[2 * 2 * 4096];   // [pair][buf][128x32]
  const int t = threadIdx.x;
  const int wave = t >> 6, lane = t & 63;
  const int col = lane & 15, quad = lane >> 4;
  const int pair = wave >> 1;        // key-half
  const int pw = wave & 1;           // row-set group within pair
  // XCD swizzle: 672 blocks = 8 XCDs x 84; each XCD gets a contiguous run of
  // (head, qblock) so its private L2 holds ~1.5 heads of K/V (~2.8 MB).
  const int d = blockIdx.y * 56 + blockIdx.x;
  const int wk = (d & 7) * 84 + (d >> 3);
  const int h = wk / 56;
  const int qb = wk - h * 56;
  const int q0 = qb * 64;
  const int vview = q0 / VS;
  const int fidx = (q0 % VS) / TPF;
  const int base0 = vview * VS;
  const int base1 = (1 - vview) * VS + fidx * TPF;
  const int jmpd = base1 - base0 - 1760;   // tile55 -> tile56 token delta

  // ---- Q fragments straight from global: rows q0 + pw*32 + col (A), +16 (B) ----
  const u16* qrow = q + (size_t)(q0 + pw * 32 + col) * DMODEL + h * HDIM;
  bf16x8 qfA[4], qfB[4];
#pragma unroll
  for (int c = 0; c < 4; ++c) {
    qfA[c] = *(const bf16x8*)(qrow + ((c * 4 + quad) << 3));
    qfB[c] = *(const bf16x8*)(qrow + 16 * DMODEL + ((c * 4 + quad) << 3));
  }
  asm volatile("" ::: "memory");

  // ---- per-lane staging sources (pre-swizzled), 4 K + 4 V per wave ----
  // K: chunk swizzle k4(key)=((key>>1)&12)|(key&3); permuted read rows
  // pi(col), pi(col)+4 see XOR key4 == col -> s0/s1 = keys 8*quad..8*quad+7.
  const int pstart = pair * 35;                    // first tile of this pair
  const u16* ksrc[4];
  const u16* vsrc[4];
#pragma unroll
  for (int j = 0; j < 4; ++j) {
    const int ci = (pw * 4 + j) * 64 + lane;      // 0..511
    const int key = ci >> 4, c = ci & 15;         // key 0..31
    const int k4 = ((key >> 1) & 12) | (key & 3);
    ksrc[j] = k + (size_t)(base0 + pstart * 32 + key) * DMODEL + h * HDIM +
              ((c ^ k4) << 3);
    const int hd = ci >> 2, sl = ci & 3;          // hd 0..127
    vsrc[j] = vt + (size_t)(h * HDIM + hd) * TS + base0 + pstart * 32 +
              ((sl ^ (hd & 3)) << 3);
  }
  // loop-invariant LDS read offsets (u16 units)
  const int r0 = ((col & 12) << 1) | (col & 3);   // pi(col)
  int koffu[4];
#pragma unroll
  for (int c = 0; c < 4; ++c)
    koffu[c] = pair * 8192 + r0 * 128 + (((c * 4 + quad) ^ col) << 3);
  const int voffu = pair * 8192 + col * 32 + ((quad ^ (col & 3)) << 3);

  // ---- prologue: stage pair's tile 0 into buf0 ----
#pragma unroll
  for (int j = 0; j < 4; ++j) {
    gl16(ksrc[j], &Kls[pair * 8192 + (pw * 4 + j) * 512]);
    gl16(vsrc[j], &Vls[pair * 8192 + (pw * 4 + j) * 512]);
  }
  int ts = pstart + 1;   // next tile to stage
#pragma unroll
  for (int j = 0; j < 4; ++j) { ksrc[j] += 32 * DMODEL; vsrc[j] += 32; }

  f32x4 accA[8], accB[8];
#pragma unroll
  for (int c = 0; c < 8; ++c) {
    accA[c] = (f32x4){0.f, 0.f, 0.f, 0.f};
    accB[c] = (f32x4){0.f, 0.f, 0.f, 0.f};
  }
  float mA = -1e30f, lA = 0.f, mB = -1e30f, lB = 0.f;

#define AITER(CUR, LAST)                                                       \
  do {                                                                         \
    if (!(LAST)) {                                                             \
      _Pragma("unroll") for (int j = 0; j < 4; ++j) {                          \
        gl16(ksrc[j], &Kls[pair * 8192 + ((CUR) ^ 1) * 4096 + (pw * 4 + j) * 512]); \
        gl16(vsrc[j], &Vls[pair * 8192 + ((CUR) ^ 1) * 4096 + (pw * 4 + j) * 512]); \
      }                                                                        \
      const int dd = (ts == 55) ? jmpd : 32; ++ts;                             \
      _Pragma("unroll") for (int j = 0; j < 4; ++j) {                          \
        ksrc[j] += (ptrdiff_t)dd * DMODEL; vsrc[j] += dd;                      \
      }                                                                        \
    }                                                                          \
    asm volatile("s_waitcnt vmcnt(%0)" ::"i"((LAST) ? 0 : 8) : "memory");      \
    __builtin_amdgcn_s_barrier();                                              \
    asm volatile("" ::: "memory");                                             \
    f32x4 s0a = (f32x4){0.f, 0.f, 0.f, 0.f}, s1a = s0a, s0b = s0a, s1b = s0a;  \
    __builtin_amdgcn_s_setprio(1);                                             \
    _Pragma("unroll") for (int c = 0; c < 4; ++c) {                            \
      bf16x8 ka0 = *(const bf16x8*)&Kls[(CUR) * 4096 + koffu[c]];              \
      bf16x8 ka1 = *(const bf16x8*)&Kls[(CUR) * 4096 + koffu[c] + 512];        \
      s0a = __builtin_amdgcn_mfma_f32_16x16x32_bf16(ka0, qfA[c], s0a, 0, 0, 0);\
      s1a = __builtin_amdgcn_mfma_f32_16x16x32_bf16(ka1, qfA[c], s1a, 0, 0, 0);\
      s0b = __builtin_amdgcn_mfma_f32_16x16x32_bf16(ka0, qfB[c], s0b, 0, 0, 0);\
      s1b = __builtin_amdgcn_mfma_f32_16x16x32_bf16(ka1, qfB[c], s1b, 0, 0, 0);\
    }                                                                          \
    __builtin_amdgcn_s_setprio(0);                                             \
    float lmaxA = fmaxf(fmaxf(fmaxf(s0a[0], s0a[1]), fmaxf(s0a[2], s0a[3])),   \
                        fmaxf(fmaxf(s1a[0], s1a[1]), fmaxf(s1a[2], s1a[3])));  \
    float lmaxB = fmaxf(fmaxf(fmaxf(s0b[0], s0b[1]), fmaxf(s0b[2], s0b[3])),   \
                        fmaxf(fmaxf(s1b[0], s1b[1]), fmaxf(s1b[2], s1b[3])));  \
    lmaxA = fmaxf(lmaxA, __shfl_xor(lmaxA, 16));                               \
    lmaxA = fmaxf(lmaxA, __shfl_xor(lmaxA, 32));                               \
    lmaxB = fmaxf(lmaxB, __shfl_xor(lmaxB, 16));                               \
    lmaxB = fmaxf(lmaxB, __shfl_xor(lmaxB, 32));                               \
    if (__any(fmaxf(lmaxA - mA, lmaxB - mB) > 8.f)) {                          \
      const float mnA = fmaxf(mA, lmaxA), mnB = fmaxf(mB, lmaxB);              \
      const float aA = exp2fast(mA - mnA), aB = exp2fast(mB - mnB);            \
      _Pragma("unroll") for (int c = 0; c < 8; ++c) {                          \
        accA[c][0] *= aA; accA[c][1] *= aA; accA[c][2] *= aA; accA[c][3] *= aA;\
        accB[c][0] *= aB; accB[c][1] *= aB; accB[c][2] *= aB; accB[c][3] *= aB;\
      }                                                                        \
      lA *= aA; lB *= aB; mA = mnA; mB = mnB;                                  \
    }                                                                          \
    float psA = 0.f, psB = 0.f;                                                \
    _Pragma("unroll") for (int r = 0; r < 4; ++r) {                            \
      s0a[r] = exp2fast(s0a[r] - mA); s1a[r] = exp2fast(s1a[r] - mA);          \
      s0b[r] = exp2fast(s0b[r] - mB); s1b[r] = exp2fast(s1b[r] - mB);          \
      psA += s0a[r] + s1a[r]; psB += s0b[r] + s1b[r];                          \
    }                                                                          \
    union { u32 w[4]; bf16x8 v; } puA, puB;                                    \
    asm("v_cvt_pk_bf16_f32 %0, %1, %2" : "=v"(puA.w[0]) : "v"(s0a[0]), "v"(s0a[1])); \
    asm("v_cvt_pk_bf16_f32 %0, %1, %2" : "=v"(puA.w[1]) : "v"(s0a[2]), "v"(s0a[3])); \
    asm("v_cvt_pk_bf16_f32 %0, %1, %2" : "=v"(puA.w[2]) : "v"(s1a[0]), "v"(s1a[1])); \
    asm("v_cvt_pk_bf16_f32 %0, %1, %2" : "=v"(puA.w[3]) : "v"(s1a[2]), "v"(s1a[3])); \
    asm("v_cvt_pk_bf16_f32 %0, %1, %2" : "=v"(puB.w[0]) : "v"(s0b[0]), "v"(s0b[1])); \
    asm("v_cvt_pk_bf16_f32 %0, %1, %2" : "=v"(puB.w[1]) : "v"(s0b[2]), "v"(s0b[3])); \
    asm("v_cvt_pk_bf16_f32 %0, %1, %2" : "=v"(puB.w[2]) : "v"(s1b[0]), "v"(s1b[1])); \
    asm("v_cvt_pk_bf16_f32 %0, %1, %2" : "=v"(puB.w[3]) : "v"(s1b[2]), "v"(s1b[3])); \
    __builtin_amdgcn_s_setprio(1);                                             \
    _Pragma("unroll") for (int c = 0; c < 8; ++c) {                            \
      bf16x8 va = *(const bf16x8*)&Vls[(CUR) * 4096 + voffu + c * 512];        \
      accA[c] = __builtin_amdgcn_mfma_f32_16x16x32_bf16(va, puA.v, accA[c], 0, 0, 0); \
      accB[c] = __builtin_amdgcn_mfma_f32_16x16x32_bf16(va, puB.v, accB[c], 0, 0, 0); \
    }                                                                          \
    __builtin_amdgcn_s_setprio(0);                                             \
    if (!(LAST)) {                                                             \
      asm volatile("" ::: "memory");                                           \
      __builtin_amdgcn_s_barrier();                                            \
      asm volatile("" ::: "memory");                                           \
    }                                                                          \
    psA += __shfl_xor(psA, 16);                                                \
    psA += __shfl_xor(psA, 32);                                                \
    psB += __shfl_xor(psB, 16);                                                \
    psB += __shfl_xor(psB, 32);                                                \
    lA += psA; lB += psB;                                                      \
  } while (0)

  for (int tt = 0; tt < 17; ++tt) {   // pair-local tiles 0..33
    AITER(0, false);
    AITER(1, false);
  }
  AITER(0, true);                     // pair-local tile 34
#undef AITER

  // ---- merge partner pairs (wave ^ 2) via LDS LSE-combine ----
  __syncthreads();                    // all compute done before LDS reuse
  float* M = (float*)Kls;             // 2 regions x 4096 floats (16 KB each)
  float* S = (float*)Vls;             // scalars
  if (wave >= 2) {
    const int rg = pw * 4096;
#pragma unroll
    for (int c = 0; c < 8; ++c)
#pragma unroll
      for (int r = 0; r < 4; ++r) {
        M[rg + (c * 4 + r) * 64 + lane] = accA[c][r];
        M[rg + 2048 + (c * 4 + r) * 64 + lane] = accB[c][r];
      }
    S[pw * 256 + lane] = mA;
    S[pw * 256 + 64 + lane] = lA;
    S[pw * 256 + 128 + lane] = mB;
    S[pw * 256 + 192 + lane] = lB;
  }
  __syncthreads();
  if (wave < 2) {
    const int rg = pw * 4096;
    const float mAp = S[pw * 256 + lane];
    const float lAp = S[pw * 256 + 64 + lane];
    const float mBp = S[pw * 256 + 128 + lane];
    const float lBp = S[pw * 256 + 192 + lane];
    const float muA = fmaxf(mA, mAp), muB = fmaxf(mB, mBp);
    const float sA = exp2fast(mA - muA), xA = exp2fast(mAp - muA);
    const float sB = exp2fast(mB - muB), xB = exp2fast(mBp - muB);
    const float invA = 1.0f / (lA * sA + lAp * xA);
    const float invB = 1.0f / (lB * sB + lBp * xB);
    u16* orowA = fused + (size_t)(q0 + pw * 32 + col) * DMODEL + h * HDIM;
    u16* orowB = orowA + 16 * DMODEL;
#pragma unroll
    for (int c = 0; c < 8; ++c) {
      float fa[4], fb[4];
#pragma unroll
      for (int r = 0; r < 4; ++r) {
        fa[r] = (accA[c][r] * sA + M[rg + (c * 4 + r) * 64 + lane] * xA) * invA;
        fb[r] = (accB[c][r] * sB + M[rg + 2048 + (c * 4 + r) * 64 + lane] * xB) * invB;
      }
      uint2 oa, ob;
      oa.x = (u32)f2b(fa[0]) | ((u32)f2b(fa[1]) << 16);
      oa.y = (u32)f2b(fa[2]) | ((u32)f2b(fa[3]) << 16);
      ob.x = (u32)f2b(fb[0]) | ((u32)f2b(fb[1]) << 16);
      ob.y = (u32)f2b(fb[2]) | ((u32)f2b(fb[3]) << 16);
      *(uint2*)(orowA + c * 16 + quad * 4) = oa;
      *(uint2*)(orowB + c * 16 + quad * 4) = ob;
    }
  }
}

extern "C" void kernel_launch(void* const* d_in, const int* in_sizes, int n_in,
                              void* d_out, int out_size, void* d_ws, size_t ws_size,
                              hipStream_t stream) {
  (void)in_sizes; (void)n_in; (void)out_size; (void)ws_size;
  const float* x   = (const float*)d_in[0];
  const float* fr  = (const float*)d_in[1];
  const float* qw  = (const float*)d_in[2];
  const float* qb  = (const float*)d_in[3];
  const float* kw  = (const float*)d_in[4];
  const float* kb  = (const float*)d_in[5];
  const float* vw  = (const float*)d_in[6];
  const float* vb  = (const float*)d_in[7];
  const float* ow  = (const float*)d_in[8];
  const float* ob  = (const float*)d_in[9];
  const float* nqw = (const float*)d_in[10];
  const float* nkw = (const float*)d_in[11];

  // ws (bf16 elems): qf(->fused) | (unused) | xb | wqkv(3x1536x1536) | owb.
  // d_out (fp32, 22 MB) dead until gemm_out: kf lower 11 MB, vtb upper 11 MB.
  u16* qf   = (u16*)d_ws;
  u16* vf   = qf + (size_t)TS * DMODEL;   // unused (v goes straight to vtb)
  u16* xb   = vf + (size_t)TS * DMODEL;
  u16* wqkv = xb + (size_t)TS * DMODEL;
  u16* owb  = wqkv + (size_t)3 * DMODEL * DMODEL;
  u16* kf   = (u16*)d_out;
  u16* vtb  = (u16*)d_out + (size_t)TS * DMODEL;

  convert_bf16<<<dim3(TS * DMODEL / 8 / 256, 5), dim3(256), 0, stream>>>(
      x, qw, kw, vw, ow, xb, wqkv, owb);
  gemm_mfma<true><<<dim3(3 * DMODEL / 128, TS / 128), dim3(256), 0, stream>>>(
      xb, wqkv, qb, kb, vb, qf, kf, vtb, nullptr);
  rmsnorm_rope<<<dim3(TS, 2), dim3(256), 0, stream>>>(qf, kf, fr, nqw, nkw);
  attn_mfma<<<dim3(TS / 64, NHEAD), dim3(256), 0, stream>>>(qf, kf, vtb, qf);
  gemm_mfma<false><<<dim3(DMODEL / 128, TS / 128), dim3(256), 0, stream>>>(
      qf, owb, ob, nullptr, nullptr, nullptr, nullptr, nullptr, (float*)d_out);
}

// Round 7
// 310.274 us; speedup vs baseline: 1.2487x; 1.2487x over previous
//
#include <hip/hip_runtime.h>

#define TS 3584
#define VS 1792
#define TPF 448
#define NHEAD 12
#define HDIM 128
#define DMODEL 1536
// ATTN_SCALE * log2(e): folded into q during rmsnorm_rope so QK^T scores are
// already in log2 domain (softmax uses exp2).
#define QK_PRESCALE (0.08838834764831845f * 1.4426950408889634f)

typedef unsigned short u16;
typedef unsigned int u32;
typedef unsigned long long u64;
typedef __attribute__((ext_vector_type(8))) short bf16x8;
typedef __attribute__((ext_vector_type(4))) float f32x4;

__device__ __forceinline__ float u2f(u32 u) { union { u32 u; float f; } c; c.u = u; return c.f; }
__device__ __forceinline__ float blo(u32 u) { return u2f(u << 16); }
__device__ __forceinline__ float bhi(u32 u) { return u2f(u & 0xffff0000u); }
__device__ __forceinline__ u16 f2b(float f) {
  union { float f; u32 u; } c; c.f = f;
  return (u16)((c.u + 0x7fffu + ((c.u >> 16) & 1u)) >> 16);
}

__device__ __forceinline__ float exp2fast(float x) {
#if __has_builtin(__builtin_amdgcn_exp2f)
  return __builtin_amdgcn_exp2f(x);
#else
  float r; asm("v_exp_f32 %0, %1" : "=v"(r) : "v"(x)); return r;
#endif
}

// async global -> LDS, 16B per lane; LDS dest is wave-uniform base
// (HW writes base + lane*16), global src is per-lane (pre-swizzled).
__device__ __forceinline__ void gl16(const u16* g, u16* l) {
  __builtin_amdgcn_global_load_lds(
      (const __attribute__((address_space(1))) void*)g,
      (__attribute__((address_space(3))) void*)l, 16, 0, 0);
}

// Pack fp32 tensors to bf16 (RNE). z: 0=x, 1..3=q/k/v weights (concat), 4=o_w.
__global__ __launch_bounds__(256) void convert_bf16(
    const float* __restrict__ x, const float* __restrict__ qw,
    const float* __restrict__ kw, const float* __restrict__ vw,
    const float* __restrict__ ow, u16* __restrict__ xb,
    u16* __restrict__ wqkv, u16* __restrict__ owb) {
  const int z = blockIdx.y;
  const float* src;
  u16* dst;
  int n8;
  if (z == 0)      { src = x;  dst = xb;  n8 = TS * DMODEL / 8; }
  else if (z == 4) { src = ow; dst = owb; n8 = DMODEL * DMODEL / 8; }
  else {
    src = (z == 1) ? qw : (z == 2) ? kw : vw;
    dst = wqkv + (size_t)(z - 1) * DMODEL * DMODEL;
    n8 = DMODEL * DMODEL / 8;
  }
  const int idx = blockIdx.x * 256 + threadIdx.x;
  if (idx >= n8) return;
  const float4 a = ((const float4*)src)[2 * idx];
  const float4 b = ((const float4*)src)[2 * idx + 1];
  uint4 o;
  o.x = (u32)f2b(a.x) | ((u32)f2b(a.y) << 16);
  o.y = (u32)f2b(a.z) | ((u32)f2b(a.w) << 16);
  o.z = (u32)f2b(b.x) | ((u32)f2b(b.y) << 16);
  o.w = (u32)f2b(b.z) | ((u32)f2b(b.w) << 16);
  ((uint4*)dst)[idx] = o;
}

// MFMA NT GEMM: C[m,n] = sum_k A[m,k]*W[n,k] + bias[n]. A,W bf16 K-major, K=1536.
// 128x128 tile, BK=64, 256 thr = 4 waves, each wave 64x64 via 4x4 mfma 16x16x32.
// Staging via global_load_lds (pre-swizzled global src) + bijective XCD swizzle.
// QKV v-section blocks (exactly one head wide) write vt TRANSPOSED directly
// via a swizzled LDS bounce -> no separate transpose kernel.
template <bool QKV>
__global__ __launch_bounds__(256) void gemm_mfma(
    const u16* __restrict__ A, const u16* __restrict__ W,
    const float* __restrict__ b0, const float* __restrict__ b1,
    const float* __restrict__ b2,
    u16* __restrict__ o0, u16* __restrict__ o1, u16* __restrict__ o2,
    float* __restrict__ of) {
  __shared__ __align__(16) u16 SH[128 * 128];   // Als | Bls; reused by v-epilogue
  u16* const Als = SH;
  u16* const Bls = SH + 128 * 64;
  const int t = threadIdx.x;
  const int wave = t >> 6, lane = t & 63, col = lane & 15, quad = lane >> 4;
  // XCD swizzle (grids are multiples of 8 -> simple form is bijective).
  const int nwg = gridDim.x * gridDim.y;
  const int dlin = blockIdx.y * gridDim.x + blockIdx.x;
  const int wk = (dlin & 7) * (nwg >> 3) + (dlin >> 3);
  const int by = wk / gridDim.x, bx = wk - by * gridDim.x;
  const int m0 = by * 128, n0 = bx * 128;
  const int wm = (wave & 1) * 64, wn = (wave >> 1) * 64;

  // per-lane pre-swizzled staging sources: LDS linear dest idx*8 holds
  // global chunk (idx&7)^((idx>>3)&7) of row idx>>3 (matches read swizzle).
  const int srow = lane >> 3;                  // 0..7
  const int sch = (lane & 7) ^ srow;           // source chunk
  const u16* pA[4];
  const u16* pB[4];
#pragma unroll
  for (int i = 0; i < 4; ++i) {
    const int r = i * 32 + wave * 8 + srow;
    pA[i] = A + (size_t)(m0 + r) * DMODEL + sch * 8;
    pB[i] = W + (size_t)(n0 + r) * DMODEL + sch * 8;
  }

  f32x4 acc[4][4];
#pragma unroll
  for (int i = 0; i < 4; ++i)
#pragma unroll
    for (int j = 0; j < 4; ++j) acc[i][j] = (f32x4){0.f, 0.f, 0.f, 0.f};

  for (int k0 = 0; k0 < DMODEL; k0 += 64) {
    __syncthreads();
#pragma unroll
    for (int i = 0; i < 4; ++i) {
      gl16(pA[i] + k0, &Als[i * 2048 + wave * 512]);
      gl16(pB[i] + k0, &Bls[i * 2048 + wave * 512]);
    }
    __syncthreads();   // compiler drains vmcnt before s_barrier
#pragma unroll
    for (int s = 0; s < 2; ++s) {
      bf16x8 af[4], bv[4];
#pragma unroll
      for (int i = 0; i < 4; ++i) {
        const int r = wm + i * 16 + col;
        af[i] = *(const bf16x8*)&Als[r * 64 + (((s * 4 + quad) ^ (r & 7)) * 8)];
      }
#pragma unroll
      for (int j = 0; j < 4; ++j) {
        const int r = wn + j * 16 + col;
        bv[j] = *(const bf16x8*)&Bls[r * 64 + (((s * 4 + quad) ^ (r & 7)) * 8)];
      }
#pragma unroll
      for (int i = 0; i < 4; ++i)
#pragma unroll
        for (int j = 0; j < 4; ++j)
          acc[i][j] = __builtin_amdgcn_mfma_f32_16x16x32_bf16(af[i], bv[j], acc[i][j], 0, 0, 0);
    }
  }

  if constexpr (QKV) {
    const int sec = n0 / DMODEL;   // block-uniform (128-wide sections)
    if (sec == 2) {
      // ---- fused V transpose: acc -> LDS [hd][tok] (chunk-XOR swizzle) -> vt ----
      __syncthreads();             // all waves done reading Als/Bls
#pragma unroll
      for (int j = 0; j < 4; ++j) {
        const int hdl = wn + j * 16 + col;           // 0..127 (= head-local hd)
        const float bias = b2[n0 - 2 * DMODEL + hdl];
#pragma unroll
        for (int i = 0; i < 4; ++i) {
          const int tokl = wm + i * 16 + quad * 4;   // 0..124 (4 consecutive)
          u64 pk = (u64)f2b(acc[i][j][0] + bias) |
                   ((u64)f2b(acc[i][j][1] + bias) << 16) |
                   ((u64)f2b(acc[i][j][2] + bias) << 32) |
                   ((u64)f2b(acc[i][j][3] + bias) << 48);
          *(u64*)&SH[hdl * 128 + (((tokl >> 3) ^ (hdl & 15)) * 8) + (tokl & 7)] = pk;
        }
      }
      __syncthreads();
      const int hgl = (n0 - 2 * DMODEL) >> 7;        // global head
#pragma unroll
      for (int it = 0; it < 8; ++it) {
        const int idx = t + it * 256;
        const int row = idx >> 4, ch = idx & 15;
        uint4 w = *(const uint4*)&SH[row * 128 + ((ch ^ (row & 15)) * 8)];
        *(uint4*)(o2 + (size_t)(hgl * HDIM + row) * TS + m0 + ch * 8) = w;
      }
      return;
    }
    // ---- q / k sections: row-major bf16 + bias ----
    u16* dst = (sec == 0) ? o0 : o1;
    const float* bp = (sec == 0) ? b0 : b1;
#pragma unroll
    for (int j = 0; j < 4; ++j) {
      const int nn = n0 - sec * DMODEL + wn + j * 16 + col;
      const float bias = bp[nn];
#pragma unroll
      for (int i = 0; i < 4; ++i) {
        const int mb = m0 + wm + i * 16 + quad * 4;
#pragma unroll
        for (int r = 0; r < 4; ++r)
          dst[(size_t)(mb + r) * DMODEL + nn] = f2b(acc[i][j][r] + bias);
      }
    }
  } else {
#pragma unroll
    for (int j = 0; j < 4; ++j) {
      const int ng = n0 + wn + j * 16 + col;
      const float bias = b0[ng];
#pragma unroll
      for (int i = 0; i < 4; ++i) {
        const int mb = m0 + wm + i * 16 + quad * 4;
#pragma unroll
        for (int r = 0; r < 4; ++r)
          of[(size_t)(mb + r) * DMODEL + ng] = acc[i][j][r] + bias;
      }
    }
  }
}

// In-place RMSNorm(+weight) then RoPE on bf16 rows. blockIdx.x = token; y: 0=q,1=k.
__global__ __launch_bounds__(256) void rmsnorm_rope(
    u16* qbuf, u16* kbuf, const float* __restrict__ freqs,
    const float* __restrict__ nqw, const float* __restrict__ nkw) {
  const int tok = blockIdx.x;
  u32* row = (u32*)((blockIdx.y == 0 ? qbuf : kbuf) + (size_t)tok * DMODEL);
  const float* w = blockIdx.y == 0 ? nqw : nkw;
  const int t = threadIdx.x;
  const u32 u0 = row[t], u1 = row[t + 256], u2 = row[t + 512];
  float px[3] = { blo(u0), blo(u1), blo(u2) };
  float py[3] = { bhi(u0), bhi(u1), bhi(u2) };
  float ss = px[0] * px[0] + py[0] * py[0] + px[1] * px[1] + py[1] * py[1] +
             px[2] * px[2] + py[2] * py[2];
#pragma unroll
  for (int off = 32; off; off >>= 1) ss += __shfl_xor(ss, off);
  __shared__ float red[4];
  if ((t & 63) == 0) red[t >> 6] = ss;
  __syncthreads();
  float rstd = rsqrtf((red[0] + red[1] + red[2] + red[3]) * (1.0f / DMODEL) + 1e-6f);
  if (blockIdx.y == 0) rstd *= QK_PRESCALE;
  const int p = tok % VS;
  const int fi = p / TPF, rem = p % TPF, hi = rem / 28, wi = rem % 28;
#pragma unroll
  for (int jj = 0; jj < 3; ++jj) {
    const int pj = t + jj * 256;
    const int i = pj & 63;
    const int prow = (i < 22) ? fi : ((i < 43) ? hi : wi);
    const float ang = freqs[prow * 64 + i];
    float sn, cs;
    sincosf(ang, &sn, &cs);
    const float a = px[jj] * rstd * w[2 * pj], b = py[jj] * rstd * w[2 * pj + 1];
    row[pj] = (u32)f2b(a * cs - b * sn) | ((u32)f2b(a * sn + b * cs) << 16);
  }
}

// MFMA flash attention over union key set (in-view 1792 + cross-view same-frame 448).
// v8 = v4 verbatim (best measured: 101.5 us): KVBLK=32, K AND V double-buffered
// (prefetch distance = 1 full iteration, 2-barrier schedule), Q in registers
// (LDS 32KB), unroll x2 (compile-time buffer index), in-register P via permuted
// K rows, exp2 softmax, defer-max, setprio.
__global__ __launch_bounds__(256) void attn_mfma(
    const u16* __restrict__ q, const u16* __restrict__ k,
    const u16* __restrict__ vt, u16* __restrict__ fused) {
  __shared__ __align__(16) u16 Kls[2 * 32 * 128];   // 2 bufs x 8KB
  __shared__ __align__(16) u16 Vls[2 * 128 * 32];   // 2 bufs x 8KB
  const int t = threadIdx.x;
  const int wave = t >> 6, lane = t & 63;
  const int col = lane & 15, quad = lane >> 4;
  // XCD swizzle: 672 blocks = 8 XCDs x 84; each XCD gets a contiguous run of
  // (head, qblock) so its private L2 holds ~1.5 heads of K/V (~2.8 MB).
  const int d = blockIdx.y * 56 + blockIdx.x;
  const int wk = (d & 7) * 84 + (d >> 3);
  const int h = wk / 56;
  const int qb = wk - h * 56;
  const int q0 = qb * 64;
  const int vview = q0 / VS;
  const int fidx = (q0 % VS) / TPF;
  const int base0 = vview * VS;
  const int base1 = (1 - vview) * VS + fidx * TPF;
  const int jmpd = base1 - base0 - 1760;   // tile55 -> tile56 token delta

  // ---- Q fragments straight from global ----
  bf16x8 qfrag[4];
#pragma unroll
  for (int c = 0; c < 4; ++c)
    qfrag[c] = *(const bf16x8*)(q + (size_t)(q0 + wave * 16 + col) * DMODEL +
                                h * HDIM + ((c * 4 + quad) << 3));
  asm volatile("" ::: "memory");   // pin Q loads before K staging (vmcnt order)

  // ---- per-lane staging sources (pre-swizzled) ----
  // K: chunk swizzle k4(key)=((key>>1)&12)|(key&3); permuted read rows
  // pi(col), pi(col)+4 see XOR key4 == col -> s0/s1 = keys 8*quad..8*quad+7.
  const u16* ksrc[2];
  const u16* vsrc[2];
#pragma unroll
  for (int j = 0; j < 2; ++j) {
    const int ci = (wave * 2 + j) * 64 + lane;    // 0..511
    const int key = ci >> 4, c = ci & 15;         // key 0..31
    const int k4 = ((key >> 1) & 12) | (key & 3);
    ksrc[j] = k + (size_t)(base0 + key) * DMODEL + h * HDIM + ((c ^ k4) << 3);
    const int hd = ci >> 2, sl = ci & 3;          // hd 0..127
    vsrc[j] = vt + (size_t)(h * HDIM + hd) * TS + base0 + ((sl ^ (hd & 3)) << 3);
  }
  // loop-invariant LDS read offsets (u16 units)
  const int r0 = ((col & 12) << 1) | (col & 3);   // pi(col)
  int koffu[4];
#pragma unroll
  for (int c = 0; c < 4; ++c) koffu[c] = r0 * 128 + (((c * 4 + quad) ^ col) << 3);
  const int voffu = col * 32 + ((quad ^ (col & 3)) << 3);

  // ---- prologue: stage tile 0 into buf0 ----
#pragma unroll
  for (int j = 0; j < 2; ++j) {
    gl16(ksrc[j], &Kls[(wave * 2 + j) * 512]);
    gl16(vsrc[j], &Vls[(wave * 2 + j) * 512]);
  }
  int ts = 1;   // next tile to stage
#pragma unroll
  for (int j = 0; j < 2; ++j) { ksrc[j] += 32 * DMODEL; vsrc[j] += 32; }

  f32x4 accO[8];
#pragma unroll
  for (int c = 0; c < 8; ++c) accO[c] = (f32x4){0.f, 0.f, 0.f, 0.f};
  float m_run = -1e30f, l_run = 0.f;

#define AITER(CUR, LAST)                                                       \
  do {                                                                         \
    if (!(LAST)) {                                                             \
      _Pragma("unroll") for (int j = 0; j < 2; ++j) {                          \
        gl16(ksrc[j], &Kls[((CUR) ^ 1) * 4096 + (wave * 2 + j) * 512]);        \
        gl16(vsrc[j], &Vls[((CUR) ^ 1) * 4096 + (wave * 2 + j) * 512]);        \
      }                                                                        \
      const int dd = (ts == 55) ? jmpd : 32; ++ts;                             \
      _Pragma("unroll") for (int j = 0; j < 2; ++j) {                          \
        ksrc[j] += (ptrdiff_t)dd * DMODEL; vsrc[j] += dd;                      \
      }                                                                        \
    }                                                                          \
    asm volatile("s_waitcnt vmcnt(%0)" ::"i"((LAST) ? 0 : 4) : "memory");      \
    __builtin_amdgcn_s_barrier();                                              \
    asm volatile("" ::: "memory");                                             \
    f32x4 s0 = (f32x4){0.f, 0.f, 0.f, 0.f}, s1 = s0;                           \
    __builtin_amdgcn_s_setprio(1);                                             \
    _Pragma("unroll") for (int c = 0; c < 4; ++c) {                            \
      bf16x8 ka0 = *(const bf16x8*)&Kls[(CUR) * 4096 + koffu[c]];              \
      bf16x8 ka1 = *(const bf16x8*)&Kls[(CUR) * 4096 + koffu[c] + 512];        \
      s0 = __builtin_amdgcn_mfma_f32_16x16x32_bf16(ka0, qfrag[c], s0, 0, 0, 0);\
      s1 = __builtin_amdgcn_mfma_f32_16x16x32_bf16(ka1, qfrag[c], s1, 0, 0, 0);\
    }                                                                          \
    __builtin_amdgcn_s_setprio(0);                                             \
    float lmax = fmaxf(fmaxf(fmaxf(s0[0], s0[1]), fmaxf(s0[2], s0[3])),        \
                       fmaxf(fmaxf(s1[0], s1[1]), fmaxf(s1[2], s1[3])));       \
    lmax = fmaxf(lmax, __shfl_xor(lmax, 16));                                  \
    lmax = fmaxf(lmax, __shfl_xor(lmax, 32));                                  \
    if (__any(lmax > m_run + 8.f)) {                                           \
      const float mnew = fmaxf(m_run, lmax);                                   \
      const float alpha = exp2fast(m_run - mnew);                              \
      _Pragma("unroll") for (int c = 0; c < 8; ++c) {                          \
        accO[c][0] *= alpha; accO[c][1] *= alpha;                              \
        accO[c][2] *= alpha; accO[c][3] *= alpha;                              \
      }                                                                        \
      l_run *= alpha;                                                          \
      m_run = mnew;                                                            \
    }                                                                          \
    float ps = 0.f;                                                            \
    _Pragma("unroll") for (int r = 0; r < 4; ++r) {                            \
      s0[r] = exp2fast(s0[r] - m_run); s1[r] = exp2fast(s1[r] - m_run);        \
      ps += s0[r] + s1[r];                                                     \
    }                                                                          \
    union { u32 w[4]; bf16x8 v; } pu;                                          \
    asm("v_cvt_pk_bf16_f32 %0, %1, %2" : "=v"(pu.w[0]) : "v"(s0[0]), "v"(s0[1])); \
    asm("v_cvt_pk_bf16_f32 %0, %1, %2" : "=v"(pu.w[1]) : "v"(s0[2]), "v"(s0[3])); \
    asm("v_cvt_pk_bf16_f32 %0, %1, %2" : "=v"(pu.w[2]) : "v"(s1[0]), "v"(s1[1])); \
    asm("v_cvt_pk_bf16_f32 %0, %1, %2" : "=v"(pu.w[3]) : "v"(s1[2]), "v"(s1[3])); \
    __builtin_amdgcn_s_setprio(1);                                             \
    _Pragma("unroll") for (int c = 0; c < 8; ++c) {                            \
      bf16x8 va = *(const bf16x8*)&Vls[(CUR) * 4096 + voffu + c * 512];        \
      accO[c] = __builtin_amdgcn_mfma_f32_16x16x32_bf16(va, pu.v, accO[c], 0, 0, 0); \
    }                                                                          \
    __builtin_amdgcn_s_setprio(0);                                             \
    if (!(LAST)) {                                                             \
      asm volatile("" ::: "memory");                                           \
      __builtin_amdgcn_s_barrier();                                            \
      asm volatile("" ::: "memory");                                           \
    }                                                                          \
    ps += __shfl_xor(ps, 16);                                                  \
    ps += __shfl_xor(ps, 32);                                                  \
    l_run += ps;                                                               \
  } while (0)

  for (int tt = 0; tt < 34; ++tt) {   // tiles 0..67
    AITER(0, false);
    AITER(1, false);
  }
  AITER(0, false);                    // tile 68
  AITER(1, true);                     // tile 69
#undef AITER

  const float inv = 1.0f / l_run;
  const int token = q0 + wave * 16 + col;
  u16* orow = fused + (size_t)token * DMODEL + h * HDIM;
#pragma unroll
  for (int c = 0; c < 8; ++c) {
    uint2 ov;
    ov.x = (u32)f2b(accO[c][0] * inv) | ((u32)f2b(accO[c][1] * inv) << 16);
    ov.y = (u32)f2b(accO[c][2] * inv) | ((u32)f2b(accO[c][3] * inv) << 16);
    *(uint2*)(orow + c * 16 + quad * 4) = ov;
  }
}

extern "C" void kernel_launch(void* const* d_in, const int* in_sizes, int n_in,
                              void* d_out, int out_size, void* d_ws, size_t ws_size,
                              hipStream_t stream) {
  (void)in_sizes; (void)n_in; (void)out_size; (void)ws_size;
  const float* x   = (const float*)d_in[0];
  const float* fr  = (const float*)d_in[1];
  const float* qw  = (const float*)d_in[2];
  const float* qb  = (const float*)d_in[3];
  const float* kw  = (const float*)d_in[4];
  const float* kb  = (const float*)d_in[5];
  const float* vw  = (const float*)d_in[6];
  const float* vb  = (const float*)d_in[7];
  const float* ow  = (const float*)d_in[8];
  const float* ob  = (const float*)d_in[9];
  const float* nqw = (const float*)d_in[10];
  const float* nkw = (const float*)d_in[11];

  // ws (bf16 elems): qf(->fused) | (unused) | xb | wqkv(3x1536x1536) | owb.
  // d_out (fp32, 22 MB) dead until gemm_out: kf lower 11 MB, vtb upper 11 MB.
  u16* qf   = (u16*)d_ws;
  u16* vf   = qf + (size_t)TS * DMODEL;   // unused (v goes straight to vtb)
  u16* xb   = vf + (size_t)TS * DMODEL;
  u16* wqkv = xb + (size_t)TS * DMODEL;
  u16* owb  = wqkv + (size_t)3 * DMODEL * DMODEL;
  u16* kf   = (u16*)d_out;
  u16* vtb  = (u16*)d_out + (size_t)TS * DMODEL;

  convert_bf16<<<dim3(TS * DMODEL / 8 / 256, 5), dim3(256), 0, stream>>>(
      x, qw, kw, vw, ow, xb, wqkv, owb);
  gemm_mfma<true><<<dim3(3 * DMODEL / 128, TS / 128), dim3(256), 0, stream>>>(
      xb, wqkv, qb, kb, vb, qf, kf, vtb, nullptr);
  rmsnorm_rope<<<dim3(TS, 2), dim3(256), 0, stream>>>(qf, kf, fr, nqw, nkw);
  attn_mfma<<<dim3(TS / 64, NHEAD), dim3(256), 0, stream>>>(qf, kf, vtb, qf);
  gemm_mfma<false><<<dim3(DMODEL / 128, TS / 128), dim3(256), 0, stream>>>(
      qf, owb, ob, nullptr, nullptr, nullptr, nullptr, nullptr, (float*)d_out);
}